// Round 11
// baseline (218.197 us; speedup 1.0000x reference)
//
#include <hip/hip_runtime.h>
#include <hip/hip_bf16.h>
#include <math.h>

typedef __attribute__((ext_vector_type(8))) short short8;
typedef __attribute__((ext_vector_type(4))) float f32x4;

#define TT 4096
#define DM 1024
#define NH 16
#define HD 64
#define PSTR 168   // attn LDS row stride in halfwords (84 dwords == 20 mod 32 banks)

typedef __attribute__((address_space(3))) unsigned int lds_u32;
typedef __attribute__((address_space(1))) unsigned int glb_u32;

__device__ __forceinline__ void async_cp16(const void* g, void* l) {
    __builtin_amdgcn_global_load_lds((glb_u32*)g, (lds_u32*)l, 16, 0, 0);
}

// Fused fp32 -> bf16 cast for x + Wq/Wk/Wv/Wo + Wg.
__global__ __launch_bounds__(256) void cast_all(
    const float* __restrict__ x,  const float* __restrict__ wq,
    const float* __restrict__ wk, const float* __restrict__ wv,
    const float* __restrict__ wo, const float* __restrict__ wg,
    __hip_bfloat16* __restrict__ xb,  __hip_bfloat16* __restrict__ wqb,
    __hip_bfloat16* __restrict__ wkb, __hip_bfloat16* __restrict__ wvb,
    __hip_bfloat16* __restrict__ wob, __hip_bfloat16* __restrict__ wgb)
{
    int b = blockIdx.x;
    const float* src;
    __hip_bfloat16* dst;
    size_t base;
    if (b < 4096)      { src = x;  dst = xb;  base = (size_t)b * 1024; }
    else if (b < 5120) { src = wq; dst = wqb; base = (size_t)(b - 4096) * 1024; }
    else if (b < 6144) { src = wk; dst = wkb; base = (size_t)(b - 5120) * 1024; }
    else if (b < 7168) { src = wv; dst = wvb; base = (size_t)(b - 6144) * 1024; }
    else if (b < 8192) { src = wo; dst = wob; base = (size_t)(b - 7168) * 1024; }
    else               { src = wg; dst = wgb; base = (size_t)(b - 8192) * 1024; }
    size_t i = base + (size_t)threadIdx.x * 4;
    float4 v = *(const float4*)(src + i);
    __hip_bfloat16 h0 = (__hip_bfloat16)v.x;
    __hip_bfloat16 h1 = (__hip_bfloat16)v.y;
    __hip_bfloat16 h2 = (__hip_bfloat16)v.z;
    __hip_bfloat16 h3 = (__hip_bfloat16)v.w;
    ushort4 u;
    u.x = *(unsigned short*)&h0;
    u.y = *(unsigned short*)&h1;
    u.z = *(unsigned short*)&h2;
    u.w = *(unsigned short*)&h3;
    *(ushort4*)((unsigned short*)dst + i) = u;
}

// 128x128-tile GEMM: A-fragments DIRECT from global (per-wave private, L2-hot,
// pipelines against MFMA via vmcnt -- no barrier dependence); B staged in LDS
// via global_load_lds (shared across waves). LDS 8 KB -> 4 blocks/CU.
// Fused QKV via group = blockIdx.y>>3; K/V groups also emit 32-token chunk
// means from the fp32 accumulators in the epilogue.
template <typename OutT>
__global__ __launch_bounds__(256) void gemm128(
    const __hip_bfloat16* __restrict__ A,
    const __hip_bfloat16* __restrict__ B0, const __hip_bfloat16* __restrict__ B1,
    const __hip_bfloat16* __restrict__ B2,
    const float* __restrict__ c0, const float* __restrict__ c1, const float* __restrict__ c2,
    OutT* __restrict__ O0, OutT* __restrict__ O1, OutT* __restrict__ O2,
    __hip_bfloat16* __restrict__ CK, __hip_bfloat16* __restrict__ CV)
{
    const int K = DM;
    __shared__ __align__(16) unsigned short sB[128 * 32];

    const int grp = blockIdx.y >> 3;
    const __hip_bfloat16* B = grp == 0 ? B0 : (grp == 1 ? B1 : B2);
    const float* bias       = grp == 0 ? c0 : (grp == 1 ? c1 : c2);
    OutT* O                 = grp == 0 ? O0 : (grp == 1 ? O1 : O2);

    const int tid  = threadIdx.x;
    const int w    = tid >> 6;
    const int lane = tid & 63;
    const int l16  = lane & 15;
    const int quad = lane >> 4;
    const int rowBase = blockIdx.x * 128;
    const int colBase = (blockIdx.y & 7) * 128;

    const int srow   = lane >> 2;
    const int sswz   = (srow & 3) ^ (srow >> 2);
    const int gchunk = (lane & 3) ^ sswz;
    const __hip_bfloat16* gB = B + (size_t)(colBase + w * 32 + srow) * K + gchunk * 8;
    unsigned short* lB = sB + w * 32 * 32;

    const int fswz = (l16 & 3) ^ (l16 >> 2);
    const int mrow = (w & 1) * 64;
    const int ncol = (w >> 1) * 64;

    // direct-global A fragment pointers (per-wave private rows)
    const __hip_bfloat16* aP0 = A + (size_t)(rowBase + mrow +  0 + l16) * K + quad * 8;
    const __hip_bfloat16* aP1 = aP0 + (size_t)16 * K;
    const __hip_bfloat16* aP2 = aP0 + (size_t)32 * K;
    const __hip_bfloat16* aP3 = aP0 + (size_t)48 * K;

    f32x4 acc[4][4];
#pragma unroll
    for (int i = 0; i < 4; ++i)
#pragma unroll
        for (int j = 0; j < 4; ++j) acc[i][j] = (f32x4){0.f, 0.f, 0.f, 0.f};

    for (int k0 = 0; k0 < K; k0 += 32) {
        __syncthreads();
        async_cp16(gB + k0, lB);
        async_cp16(gB + k0 + (size_t)16 * K, lB + 16 * 32);

        short8 af[4];
        af[0] = *(const short8*)(aP0 + k0);
        af[1] = *(const short8*)(aP1 + k0);
        af[2] = *(const short8*)(aP2 + k0);
        af[3] = *(const short8*)(aP3 + k0);

        __syncthreads();

        short8 bf[4];
#pragma unroll
        for (int nt = 0; nt < 4; ++nt)
            bf[nt] = *(const short8*)&sB[(ncol + nt * 16 + l16) * 32 + (quad ^ fswz) * 8];
#pragma unroll
        for (int mt = 0; mt < 4; ++mt)
#pragma unroll
            for (int nt = 0; nt < 4; ++nt)
                acc[mt][nt] = __builtin_amdgcn_mfma_f32_16x16x32_bf16(af[mt], bf[nt], acc[mt][nt], 0, 0, 0);
    }

#pragma unroll
    for (int nt = 0; nt < 4; ++nt) {
        int col = colBase + ncol + nt * 16 + l16;
        float bv = bias[col];
#pragma unroll
        for (int mt = 0; mt < 4; ++mt) {
#pragma unroll
            for (int r = 0; r < 4; ++r) {
                int row = rowBase + mrow + mt * 16 + quad * 4 + r;
                O[(size_t)row * DM + col] = (OutT)(acc[mt][nt][r] + bv);
            }
        }
    }

    // chunk means for K/V groups (fp32-accurate, zero extra global reads)
    if (grp != 0) {
        __hip_bfloat16* CC = (grp == 1) ? CK : CV;
#pragma unroll
        for (int half = 0; half < 2; ++half) {
#pragma unroll
            for (int nt = 0; nt < 4; ++nt) {
                float s = 0.f;
#pragma unroll
                for (int mt = half * 2; mt < half * 2 + 2; ++mt)
#pragma unroll
                    for (int r = 0; r < 4; ++r) s += acc[mt][nt][r];
                s += __shfl_xor(s, 16);
                s += __shfl_xor(s, 32);
                if (quad == 0) {
                    int chunk = (rowBase + mrow) / 32 + half;
                    int col = colBase + ncol + nt * 16 + l16;
                    CC[(size_t)chunk * DM + col] =
                        (__hip_bfloat16)(s * (1.f / 32.f) + bias[col]);
                }
            }
        }
    }
}

// 128x64-tile GEMM for Wo: A direct from global, B LDS-staged (4 KB LDS).
template <typename OutT>
__global__ __launch_bounds__(256) void gemm_n64(
    const __hip_bfloat16* __restrict__ A,
    const __hip_bfloat16* __restrict__ B,
    const float* __restrict__ bias,
    OutT* __restrict__ O)
{
    const int K = DM;
    __shared__ __align__(16) unsigned short sB[64 * 32];

    const int tid  = threadIdx.x;
    const int w    = tid >> 6;
    const int lane = tid & 63;
    const int l16  = lane & 15;
    const int quad = lane >> 4;
    const int rowBase = blockIdx.x * 128;
    const int colBase = blockIdx.y * 64;

    const int srow   = lane >> 2;
    const int sswz   = (srow & 3) ^ (srow >> 2);
    const int gchunk = (lane & 3) ^ sswz;
    const __hip_bfloat16* gB = B + (size_t)(colBase + w * 16 + srow) * K + gchunk * 8;
    unsigned short* lB = sB + w * 16 * 32;

    const int fswz = (l16 & 3) ^ (l16 >> 2);
    const int mrow = w * 32;

    const __hip_bfloat16* aP0 = A + (size_t)(rowBase + mrow + l16) * K + quad * 8;
    const __hip_bfloat16* aP1 = aP0 + (size_t)16 * K;

    f32x4 acc[2][4];
#pragma unroll
    for (int i = 0; i < 2; ++i)
#pragma unroll
        for (int j = 0; j < 4; ++j) acc[i][j] = (f32x4){0.f, 0.f, 0.f, 0.f};

    for (int k0 = 0; k0 < K; k0 += 32) {
        __syncthreads();
        async_cp16(gB + k0, lB);

        short8 af[2];
        af[0] = *(const short8*)(aP0 + k0);
        af[1] = *(const short8*)(aP1 + k0);

        __syncthreads();

        short8 bf[4];
#pragma unroll
        for (int nt = 0; nt < 4; ++nt)
            bf[nt] = *(const short8*)&sB[(nt * 16 + l16) * 32 + (quad ^ fswz) * 8];
#pragma unroll
        for (int mt = 0; mt < 2; ++mt)
#pragma unroll
            for (int nt = 0; nt < 4; ++nt)
                acc[mt][nt] = __builtin_amdgcn_mfma_f32_16x16x32_bf16(af[mt], bf[nt], acc[mt][nt], 0, 0, 0);
    }

#pragma unroll
    for (int nt = 0; nt < 4; ++nt) {
        int col = colBase + nt * 16 + l16;
        float bv = bias[col];
#pragma unroll
        for (int mt = 0; mt < 2; ++mt) {
#pragma unroll
            for (int r = 0; r < 4; ++r) {
                int row = rowBase + mrow + mt * 16 + quad * 4 + r;
                O[(size_t)row * DM + col] = (OutT)(acc[mt][nt][r] + bv);
            }
        }
    }
}

// Gate GEMM via MFMA: G[t,h] = sigmoid(xb[t,:] . Wgb[h,:] + bg[h]).
__global__ __launch_bounds__(256) void g_mfma(
    const __hip_bfloat16* __restrict__ xb,
    const __hip_bfloat16* __restrict__ Wgb,
    const float* __restrict__ bg,
    float* __restrict__ G)
{
    const int w    = threadIdx.x >> 6;
    const int lane = threadIdx.x & 63;
    const int l16  = lane & 15;
    const int quad = lane >> 4;
    const int t0   = (blockIdx.x * 4 + w) * 16;
    const __hip_bfloat16* ap = xb + (size_t)(t0 + l16) * DM + quad * 8;
    const __hip_bfloat16* bp = Wgb + (size_t)l16 * DM + quad * 8;
    f32x4 acc = (f32x4){0.f, 0.f, 0.f, 0.f};
#pragma unroll 4
    for (int k0 = 0; k0 < DM; k0 += 32) {
        short8 a = *(const short8*)(ap + k0);
        short8 b = *(const short8*)(bp + k0);
        acc = __builtin_amdgcn_mfma_f32_16x16x32_bf16(a, b, acc, 0, 0, 0);
    }
    float bgv = bg[l16];
#pragma unroll
    for (int r = 0; r < 4; ++r) {
        int t = t0 + quad * 4 + r;
        float z = acc[r] + bgv;
        G[t * NH + l16] = 1.f / (1.f + __expf(-z));
    }
}

// MFMA attention: 64 queries x 1 head per block (grid 64 x 16, 256 threads).
__global__ __launch_bounds__(256) void attn_mfma(
    const __hip_bfloat16* __restrict__ Q,
    const __hip_bfloat16* __restrict__ K,
    const __hip_bfloat16* __restrict__ V,
    const __hip_bfloat16* __restrict__ CK,
    const __hip_bfloat16* __restrict__ CV,
    const float* __restrict__ G,
    __hip_bfloat16* __restrict__ Aout)
{
    __shared__ alignas(16) unsigned short Pls[64 * PSTR];
    __shared__ alignas(16) unsigned short Vts[64 * PSTR];

    const int h   = blockIdx.y;
    const int t0  = blockIdx.x * 64;
    const int tid = threadIdx.x;
    const int w    = tid >> 6;
    const int lane = tid & 63;
    const int l16  = lane & 15;
    const int quad = lane >> 4;
    const float scale = 0.125f;

    const int rc0  = (t0 >= 96) ? ((t0 - 64) >> 5) : 0;
    const int cmin = rc0 > 16 ? rc0 - 16 : 0;

    const unsigned short* Vu  = (const unsigned short*)V;
    const unsigned short* CVu = (const unsigned short*)CV;

    // stage V^T (+ CV^T) into LDS via 16B row-chunk loads + packed ushort2 writes
    {
#pragma unroll
        for (int gg = 0; gg < 2; ++gg) {
            const int g = w * 2 + gg;
#pragma unroll
            for (int i = 0; i < 2; ++i) {
                const int pair = lane + 64 * i;
                if (pair < 80) {
                    const int j = pair * 2;
                    const unsigned short *s0, *s1;
                    if (j < 128) {
                        int tok0 = t0 - 64 + j; if (tok0 < 0) tok0 = 0;
                        int tok1 = t0 - 63 + j; if (tok1 < 0) tok1 = 0;
                        s0 = Vu + (size_t)tok0 * DM + h * 64 + g * 8;
                        s1 = Vu + (size_t)tok1 * DM + h * 64 + g * 8;
                    } else {
                        int c0 = cmin + (j - 128); if (c0 > 127) c0 = 127;
                        int c1 = c0 + 1;           if (c1 > 127) c1 = 127;
                        s0 = CVu + (size_t)c0 * DM + h * 64 + g * 8;
                        s1 = CVu + (size_t)c1 * DM + h * 64 + g * 8;
                    }
                    short8 v0 = *(const short8*)s0;
                    short8 v1 = *(const short8*)s1;
#pragma unroll
                    for (int e = 0; e < 8; ++e) {
                        ushort2 pk;
                        pk.x = (unsigned short)v0[e];
                        pk.y = (unsigned short)v1[e];
                        *(ushort2*)&Vts[(g * 8 + e) * PSTR + j] = pk;
                    }
                }
            }
        }
    }

    const __hip_bfloat16* qp = Q + (size_t)(t0 + w * 16 + l16) * DM + h * 64 + quad * 8;
    short8 qf0 = *(const short8*)(qp);
    short8 qf1 = *(const short8*)(qp + 32);

    f32x4 sc[8];
#pragma unroll
    for (int jt = 0; jt < 8; ++jt) {
        int j = jt * 16 + l16;
        int tok = t0 - 64 + j;
        tok = tok < 0 ? 0 : tok;
        const __hip_bfloat16* kp = K + (size_t)tok * DM + h * 64 + quad * 8;
        short8 b0 = *(const short8*)(kp);
        short8 b1 = *(const short8*)(kp + 32);
        f32x4 a = __builtin_amdgcn_mfma_f32_16x16x32_bf16(qf0, b0, (f32x4){0.f,0.f,0.f,0.f}, 0, 0, 0);
        sc[jt]  = __builtin_amdgcn_mfma_f32_16x16x32_bf16(qf1, b1, a, 0, 0, 0);
    }
    f32x4 sc2[2];
#pragma unroll
    for (int jt = 0; jt < 2; ++jt) {
        int c = cmin + jt * 16 + l16;
        if (c > 127) c = 127;
        const __hip_bfloat16* cp = CK + (size_t)c * DM + h * 64 + quad * 8;
        short8 b0 = *(const short8*)(cp);
        short8 b1 = *(const short8*)(cp + 32);
        f32x4 a = __builtin_amdgcn_mfma_f32_16x16x32_bf16(qf0, b0, (f32x4){0.f,0.f,0.f,0.f}, 0, 0, 0);
        sc2[jt] = __builtin_amdgcn_mfma_f32_16x16x32_bf16(qf1, b1, a, 0, 0, 0);
    }

    __syncthreads();

    const int rbase = w * 16 + quad * 4;
    float gl[4], g2[4];
    float mx[4], sm[4], mx2[4], sm2[4];
#pragma unroll
    for (int reg = 0; reg < 4; ++reg) {
        int rr = rbase + reg;
        int t  = t0 + rr;
        float g = G[t * NH + h];
        int rc = (t >= 96) ? ((t - 64) >> 5) : 0;
        gl[reg] = (t > 0)  ? g        : 0.f;
        g2[reg] = (rc > 0) ? (1.f - g) : 0.f;

        int jlo = rr > (64 - t0) ? rr : (64 - t0);
        int jhi = rr + 63;
        float m = -1e30f;
#pragma unroll
        for (int jt = 0; jt < 8; ++jt) {
            int j = jt * 16 + l16;
            float s = (j >= jlo && j <= jhi) ? sc[jt][reg] * scale : -1e30f;
            sc[jt][reg] = s;
            m = fmaxf(m, s);
        }
        mx[reg] = m;

        int nvis = rc < 16 ? rc : 16;
        int clo = rc - nvis, chi = rc - 1;
        float m2 = -1e30f;
#pragma unroll
        for (int jt = 0; jt < 2; ++jt) {
            int c = cmin + jt * 16 + l16;
            float s = (c >= clo && c <= chi) ? sc2[jt][reg] * scale : -1e30f;
            sc2[jt][reg] = s;
            m2 = fmaxf(m2, s);
        }
        mx2[reg] = m2;
    }
#pragma unroll
    for (int off = 1; off <= 8; off <<= 1)
#pragma unroll
        for (int reg = 0; reg < 4; ++reg) {
            mx[reg]  = fmaxf(mx[reg],  __shfl_xor(mx[reg],  off));
            mx2[reg] = fmaxf(mx2[reg], __shfl_xor(mx2[reg], off));
        }
#pragma unroll
    for (int reg = 0; reg < 4; ++reg) {
        float s = 0.f, s2 = 0.f;
#pragma unroll
        for (int jt = 0; jt < 8; ++jt) {
            float p = __expf(sc[jt][reg] - mx[reg]);
            sc[jt][reg] = p;
            s += p;
        }
#pragma unroll
        for (int jt = 0; jt < 2; ++jt) {
            float p = __expf(sc2[jt][reg] - mx2[reg]);
            sc2[jt][reg] = p;
            s2 += p;
        }
        sm[reg] = s; sm2[reg] = s2;
    }
#pragma unroll
    for (int off = 1; off <= 8; off <<= 1)
#pragma unroll
        for (int reg = 0; reg < 4; ++reg) {
            sm[reg]  += __shfl_xor(sm[reg],  off);
            sm2[reg] += __shfl_xor(sm2[reg], off);
        }

#pragma unroll
    for (int reg = 0; reg < 4; ++reg) {
        float f1 = gl[reg] / sm[reg];
        float f2 = g2[reg] / sm2[reg];
        int rowoff = (rbase + reg) * PSTR;
#pragma unroll
        for (int jt = 0; jt < 8; ++jt) {
            __hip_bfloat16 hb = (__hip_bfloat16)(sc[jt][reg] * f1);
            Pls[rowoff + jt * 16 + l16] = *(unsigned short*)&hb;
        }
#pragma unroll
        for (int jt = 0; jt < 2; ++jt) {
            __hip_bfloat16 hb = (__hip_bfloat16)(sc2[jt][reg] * f2);
            Pls[rowoff + 128 + jt * 16 + l16] = *(unsigned short*)&hb;
        }
    }
    asm volatile("s_waitcnt lgkmcnt(0)" ::: "memory");  // wave-private P round-trip

    f32x4 o[4];
#pragma unroll
    for (int nt = 0; nt < 4; ++nt) o[nt] = (f32x4){0.f, 0.f, 0.f, 0.f};
#pragma unroll
    for (int kt = 0; kt < 5; ++kt) {
        short8 a = *(const short8*)&Pls[(w * 16 + l16) * PSTR + kt * 32 + quad * 8];
#pragma unroll
        for (int nt = 0; nt < 4; ++nt) {
            int dd = nt * 16 + l16;
            short8 b = *(const short8*)&Vts[dd * PSTR + kt * 32 + quad * 8];
            o[nt] = __builtin_amdgcn_mfma_f32_16x16x32_bf16(a, b, o[nt], 0, 0, 0);
        }
    }

#pragma unroll
    for (int nt = 0; nt < 4; ++nt) {
#pragma unroll
        for (int reg = 0; reg < 4; ++reg) {
            int row = t0 + rbase + reg;
            int col = h * 64 + nt * 16 + l16;
            Aout[(size_t)row * DM + col] = (__hip_bfloat16)(o[nt][reg]);
        }
    }
}

extern "C" void kernel_launch(void* const* d_in, const int* in_sizes, int n_in,
                              void* d_out, int out_size, void* d_ws, size_t ws_size,
                              hipStream_t stream)
{
    const float* x  = (const float*)d_in[0];
    const float* Wq = (const float*)d_in[1];
    const float* bq = (const float*)d_in[2];
    const float* Wk = (const float*)d_in[3];
    const float* bk = (const float*)d_in[4];
    const float* Wv = (const float*)d_in[5];
    const float* bv = (const float*)d_in[6];
    const float* Wo = (const float*)d_in[7];
    const float* bo = (const float*)d_in[8];
    const float* Wg = (const float*)d_in[9];
    const float* bg = (const float*)d_in[10];
    float* out = (float*)d_out;

    char* ws = (char*)d_ws;
    const size_t MB = 1024 * 1024;
    __hip_bfloat16* xb  = (__hip_bfloat16*)(ws + 0 * MB);   // 8 MB
    __hip_bfloat16* Qb  = (__hip_bfloat16*)(ws + 8 * MB);   // 8 MB
    __hip_bfloat16* Kb  = (__hip_bfloat16*)(ws + 16 * MB);  // 8 MB
    __hip_bfloat16* Vb  = (__hip_bfloat16*)(ws + 24 * MB);  // 8 MB
    __hip_bfloat16* Ab  = (__hip_bfloat16*)(ws + 32 * MB);  // 8 MB
    __hip_bfloat16* Wqb = (__hip_bfloat16*)(ws + 40 * MB);  // 2 MB
    __hip_bfloat16* Wkb = (__hip_bfloat16*)(ws + 42 * MB);  // 2 MB
    __hip_bfloat16* Wvb = (__hip_bfloat16*)(ws + 44 * MB);  // 2 MB
    __hip_bfloat16* Wob = (__hip_bfloat16*)(ws + 46 * MB);  // 2 MB
    __hip_bfloat16* CKb = (__hip_bfloat16*)(ws + 48 * MB);            // 256 KB
    __hip_bfloat16* CVb = (__hip_bfloat16*)(ws + 48 * MB + 256*1024); // 256 KB
    float* Gf           = (float*)(ws + 48 * MB + 512 * 1024);        // 256 KB
    __hip_bfloat16* Wgb = (__hip_bfloat16*)(ws + 48 * MB + 768*1024); // 32 KB

    cast_all<<<dim3(8208), 256, 0, stream>>>(x, Wq, Wk, Wv, Wo, Wg,
                                             xb, Wqb, Wkb, Wvb, Wob, Wgb);

    // Gate GEMM (only needs xb/Wgb; runs before the big QKV GEMM).
    g_mfma<<<dim3(64), 256, 0, stream>>>(xb, Wgb, bg, Gf);

    // Fused QKV GEMM + chunk-mean epilogue: grid (32, 24); group = blockIdx.y>>3.
    gemm128<__hip_bfloat16><<<dim3(32, 24), 256, 0, stream>>>(
        xb, Wqb, Wkb, Wvb, bq, bk, bv, Qb, Kb, Vb, CKb, CVb);

    attn_mfma<<<dim3(64, 16), 256, 0, stream>>>(Qb, Kb, Vb, CKb, CVb, Gf, Ab);

    // Output GEMM: 128x64 tiles (BK=32), grid (32, 16).
    gemm_n64<float><<<dim3(32, 16), 256, 0, stream>>>(Ab, Wob, bo, out);
}

// Round 12
// 197.664 us; speedup vs baseline: 1.1039x; 1.1039x over previous
//
#include <hip/hip_runtime.h>
#include <hip/hip_bf16.h>
#include <math.h>

typedef __attribute__((ext_vector_type(8))) short short8;
typedef __attribute__((ext_vector_type(4))) float f32x4;

#define TT 4096
#define DM 1024
#define NH 16
#define HD 64
#define PSTR 168   // attn LDS row stride in halfwords (84 dwords == 20 mod 32 banks)

typedef __attribute__((address_space(3))) unsigned int lds_u32;
typedef __attribute__((address_space(1))) unsigned int glb_u32;

__device__ __forceinline__ void async_cp16(const void* g, void* l) {
    __builtin_amdgcn_global_load_lds((glb_u32*)g, (lds_u32*)l, 16, 0, 0);
}

__device__ __forceinline__ unsigned short bf16u(float f) {
    __hip_bfloat16 h = (__hip_bfloat16)f;
    return *(unsigned short*)&h;
}

// Fused fp32 -> bf16 cast for x + Wq/Wk/Wv/Wo + Wg, PLUS the gate GEMM
// (blocks >= 8208 read fp32 x/Wg directly -> no ordering dependency on cast).
__global__ __launch_bounds__(256) void cast_all(
    const float* __restrict__ x,  const float* __restrict__ wq,
    const float* __restrict__ wk, const float* __restrict__ wv,
    const float* __restrict__ wo, const float* __restrict__ wg,
    const float* __restrict__ bg,
    __hip_bfloat16* __restrict__ xb,  __hip_bfloat16* __restrict__ wqb,
    __hip_bfloat16* __restrict__ wkb, __hip_bfloat16* __restrict__ wvb,
    __hip_bfloat16* __restrict__ wob, __hip_bfloat16* __restrict__ wgb,
    float* __restrict__ G)
{
    int b = blockIdx.x;
    if (b < 8208) {
        const float* src;
        __hip_bfloat16* dst;
        size_t base;
        if (b < 4096)      { src = x;  dst = xb;  base = (size_t)b * 1024; }
        else if (b < 5120) { src = wq; dst = wqb; base = (size_t)(b - 4096) * 1024; }
        else if (b < 6144) { src = wk; dst = wkb; base = (size_t)(b - 5120) * 1024; }
        else if (b < 7168) { src = wv; dst = wvb; base = (size_t)(b - 6144) * 1024; }
        else if (b < 8192) { src = wo; dst = wob; base = (size_t)(b - 7168) * 1024; }
        else               { src = wg; dst = wgb; base = (size_t)(b - 8192) * 1024; }
        size_t i = base + (size_t)threadIdx.x * 4;
        float4 v = *(const float4*)(src + i);
        ushort4 u;
        u.x = bf16u(v.x); u.y = bf16u(v.y); u.z = bf16u(v.z); u.w = bf16u(v.w);
        *(ushort4*)((unsigned short*)dst + i) = u;
        return;
    }
    // gate GEMM: G[t,h] = sigmoid(x[t,:].Wg[h,:] + bg[h]); fp32 in, inline cvt.
    const int w    = threadIdx.x >> 6;
    const int lane = threadIdx.x & 63;
    const int l16  = lane & 15;
    const int quad = lane >> 4;
    const int t0   = ((b - 8208) * 4 + w) * 16;
    const float* ap = x  + (size_t)(t0 + l16) * DM + quad * 8;
    const float* bp = wg + (size_t)l16 * DM + quad * 8;
    f32x4 acc = (f32x4){0.f, 0.f, 0.f, 0.f};
    for (int k0 = 0; k0 < DM; k0 += 32) {
        float4 a0 = *(const float4*)(ap + k0);
        float4 a1 = *(const float4*)(ap + k0 + 4);
        float4 b0 = *(const float4*)(bp + k0);
        float4 b1 = *(const float4*)(bp + k0 + 4);
        short8 af, bf;
        af[0] = (short)bf16u(a0.x); af[1] = (short)bf16u(a0.y);
        af[2] = (short)bf16u(a0.z); af[3] = (short)bf16u(a0.w);
        af[4] = (short)bf16u(a1.x); af[5] = (short)bf16u(a1.y);
        af[6] = (short)bf16u(a1.z); af[7] = (short)bf16u(a1.w);
        bf[0] = (short)bf16u(b0.x); bf[1] = (short)bf16u(b0.y);
        bf[2] = (short)bf16u(b0.z); bf[3] = (short)bf16u(b0.w);
        bf[4] = (short)bf16u(b1.x); bf[5] = (short)bf16u(b1.y);
        bf[6] = (short)bf16u(b1.z); bf[7] = (short)bf16u(b1.w);
        acc = __builtin_amdgcn_mfma_f32_16x16x32_bf16(af, bf, acc, 0, 0, 0);
    }
    float bgv = bg[l16];
#pragma unroll
    for (int r = 0; r < 4; ++r) {
        int t = t0 + quad * 4 + r;
        float z = acc[r] + bgv;
        G[t * NH + l16] = 1.f / (1.f + __expf(-z));
    }
}

// 128x128-tile GEMM, BK=32, single-buffered A+B DMA staging (proven best:
// dbuf r6 -11us, BK64 r9 -9us, A-direct r11 -39us all regressed vs this).
// Fused QKV via group = blockIdx.y>>3; K/V groups emit 32-token chunk means
// from fp32 accumulators in the epilogue.
template <typename OutT>
__global__ __launch_bounds__(256) void gemm128(
    const __hip_bfloat16* __restrict__ A,
    const __hip_bfloat16* __restrict__ B0, const __hip_bfloat16* __restrict__ B1,
    const __hip_bfloat16* __restrict__ B2,
    const float* __restrict__ c0, const float* __restrict__ c1, const float* __restrict__ c2,
    OutT* __restrict__ O0, OutT* __restrict__ O1, OutT* __restrict__ O2,
    __hip_bfloat16* __restrict__ CK, __hip_bfloat16* __restrict__ CV)
{
    const int K = DM;
    __shared__ __align__(16) unsigned short sA[128 * 32];
    __shared__ __align__(16) unsigned short sB[128 * 32];

    const int grp = blockIdx.y >> 3;
    const __hip_bfloat16* B = grp == 0 ? B0 : (grp == 1 ? B1 : B2);
    const float* bias       = grp == 0 ? c0 : (grp == 1 ? c1 : c2);
    OutT* O                 = grp == 0 ? O0 : (grp == 1 ? O1 : O2);

    const int tid  = threadIdx.x;
    const int w    = tid >> 6;
    const int lane = tid & 63;
    const int l16  = lane & 15;
    const int quad = lane >> 4;
    const int rowBase = blockIdx.x * 128;
    const int colBase = (blockIdx.y & 7) * 128;

    const int srow   = lane >> 2;
    const int sswz   = (srow & 3) ^ (srow >> 2);
    const int gchunk = (lane & 3) ^ sswz;
    const __hip_bfloat16* gA = A + (size_t)(rowBase + w * 32 + srow) * K + gchunk * 8;
    const __hip_bfloat16* gB = B + (size_t)(colBase + w * 32 + srow) * K + gchunk * 8;
    unsigned short* lA = sA + w * 32 * 32;
    unsigned short* lB = sB + w * 32 * 32;

    const int fswz = (l16 & 3) ^ (l16 >> 2);
    const int mrow = (w & 1) * 64;
    const int ncol = (w >> 1) * 64;

    f32x4 acc[4][4];
#pragma unroll
    for (int i = 0; i < 4; ++i)
#pragma unroll
        for (int j = 0; j < 4; ++j) acc[i][j] = (f32x4){0.f, 0.f, 0.f, 0.f};

    for (int k0 = 0; k0 < K; k0 += 32) {
        __syncthreads();
        async_cp16(gA + k0, lA);
        async_cp16(gA + k0 + (size_t)16 * K, lA + 16 * 32);
        async_cp16(gB + k0, lB);
        async_cp16(gB + k0 + (size_t)16 * K, lB + 16 * 32);
        __syncthreads();

        short8 af[4], bf[4];
#pragma unroll
        for (int mt = 0; mt < 4; ++mt)
            af[mt] = *(const short8*)&sA[(mrow + mt * 16 + l16) * 32 + (quad ^ fswz) * 8];
#pragma unroll
        for (int nt = 0; nt < 4; ++nt)
            bf[nt] = *(const short8*)&sB[(ncol + nt * 16 + l16) * 32 + (quad ^ fswz) * 8];
#pragma unroll
        for (int mt = 0; mt < 4; ++mt)
#pragma unroll
            for (int nt = 0; nt < 4; ++nt)
                acc[mt][nt] = __builtin_amdgcn_mfma_f32_16x16x32_bf16(af[mt], bf[nt], acc[mt][nt], 0, 0, 0);
    }

#pragma unroll
    for (int nt = 0; nt < 4; ++nt) {
        int col = colBase + ncol + nt * 16 + l16;
        float bv = bias[col];
#pragma unroll
        for (int mt = 0; mt < 4; ++mt) {
#pragma unroll
            for (int r = 0; r < 4; ++r) {
                int row = rowBase + mrow + mt * 16 + quad * 4 + r;
                O[(size_t)row * DM + col] = (OutT)(acc[mt][nt][r] + bv);
            }
        }
    }

    // chunk means for K/V groups (fp32-accurate, zero extra global reads)
    if (grp != 0) {
        __hip_bfloat16* CC = (grp == 1) ? CK : CV;
#pragma unroll
        for (int half = 0; half < 2; ++half) {
#pragma unroll
            for (int nt = 0; nt < 4; ++nt) {
                float s = 0.f;
#pragma unroll
                for (int mt = half * 2; mt < half * 2 + 2; ++mt)
#pragma unroll
                    for (int r = 0; r < 4; ++r) s += acc[mt][nt][r];
                s += __shfl_xor(s, 16);
                s += __shfl_xor(s, 32);
                if (quad == 0) {
                    int chunk = (rowBase + mrow) / 32 + half;
                    int col = colBase + ncol + nt * 16 + l16;
                    CC[(size_t)chunk * DM + col] =
                        (__hip_bfloat16)(s * (1.f / 32.f) + bias[col]);
                }
            }
        }
    }
}

// 128x64-tile GEMM for Wo (BK=32, A+B staged, 12 KB LDS, 512 blocks).
template <typename OutT>
__global__ __launch_bounds__(256) void gemm_n64(
    const __hip_bfloat16* __restrict__ A,
    const __hip_bfloat16* __restrict__ B,
    const float* __restrict__ bias,
    OutT* __restrict__ O)
{
    const int K = DM;
    __shared__ __align__(16) unsigned short sA[128 * 32];
    __shared__ __align__(16) unsigned short sB[64 * 32];

    const int tid  = threadIdx.x;
    const int w    = tid >> 6;
    const int lane = tid & 63;
    const int l16  = lane & 15;
    const int quad = lane >> 4;
    const int rowBase = blockIdx.x * 128;
    const int colBase = blockIdx.y * 64;

    const int srow   = lane >> 2;
    const int sswz   = (srow & 3) ^ (srow >> 2);
    const int gchunk = (lane & 3) ^ sswz;
    const __hip_bfloat16* gA = A + (size_t)(rowBase + w * 32 + srow) * K + gchunk * 8;
    const __hip_bfloat16* gB = B + (size_t)(colBase + w * 16 + srow) * K + gchunk * 8;
    unsigned short* lA = sA + w * 32 * 32;
    unsigned short* lB = sB + w * 16 * 32;

    const int fswz = (l16 & 3) ^ (l16 >> 2);
    const int mrow = w * 32;

    f32x4 acc[2][4];
#pragma unroll
    for (int i = 0; i < 2; ++i)
#pragma unroll
        for (int j = 0; j < 4; ++j) acc[i][j] = (f32x4){0.f, 0.f, 0.f, 0.f};

    for (int k0 = 0; k0 < K; k0 += 32) {
        __syncthreads();
        async_cp16(gA + k0, lA);
        async_cp16(gA + k0 + (size_t)16 * K, lA + 16 * 32);
        async_cp16(gB + k0, lB);
        __syncthreads();

        short8 af[2], bf[4];
#pragma unroll
        for (int mt = 0; mt < 2; ++mt)
            af[mt] = *(const short8*)&sA[(mrow + mt * 16 + l16) * 32 + (quad ^ fswz) * 8];
#pragma unroll
        for (int nt = 0; nt < 4; ++nt)
            bf[nt] = *(const short8*)&sB[(nt * 16 + l16) * 32 + (quad ^ fswz) * 8];
#pragma unroll
        for (int mt = 0; mt < 2; ++mt)
#pragma unroll
            for (int nt = 0; nt < 4; ++nt)
                acc[mt][nt] = __builtin_amdgcn_mfma_f32_16x16x32_bf16(af[mt], bf[nt], acc[mt][nt], 0, 0, 0);
    }

#pragma unroll
    for (int nt = 0; nt < 4; ++nt) {
        int col = colBase + nt * 16 + l16;
        float bv = bias[col];
#pragma unroll
        for (int mt = 0; mt < 2; ++mt) {
#pragma unroll
            for (int r = 0; r < 4; ++r) {
                int row = rowBase + mrow + mt * 16 + quad * 4 + r;
                O[(size_t)row * DM + col] = (OutT)(acc[mt][nt][r] + bv);
            }
        }
    }
}

// MFMA attention: 64 queries x 1 head per block (grid 64 x 16, 256 threads).
__global__ __launch_bounds__(256) void attn_mfma(
    const __hip_bfloat16* __restrict__ Q,
    const __hip_bfloat16* __restrict__ K,
    const __hip_bfloat16* __restrict__ V,
    const __hip_bfloat16* __restrict__ CK,
    const __hip_bfloat16* __restrict__ CV,
    const float* __restrict__ G,
    __hip_bfloat16* __restrict__ Aout)
{
    __shared__ alignas(16) unsigned short Pls[64 * PSTR];
    __shared__ alignas(16) unsigned short Vts[64 * PSTR];

    const int h   = blockIdx.y;
    const int t0  = blockIdx.x * 64;
    const int tid = threadIdx.x;
    const int w    = tid >> 6;
    const int lane = tid & 63;
    const int l16  = lane & 15;
    const int quad = lane >> 4;
    const float scale = 0.125f;

    const int rc0  = (t0 >= 96) ? ((t0 - 64) >> 5) : 0;
    const int cmin = rc0 > 16 ? rc0 - 16 : 0;

    const unsigned short* Vu  = (const unsigned short*)V;
    const unsigned short* CVu = (const unsigned short*)CV;

    // stage V^T (+ CV^T) into LDS via 16B row-chunk loads + packed ushort2 writes
    {
#pragma unroll
        for (int gg = 0; gg < 2; ++gg) {
            const int g = w * 2 + gg;
#pragma unroll
            for (int i = 0; i < 2; ++i) {
                const int pair = lane + 64 * i;
                if (pair < 80) {
                    const int j = pair * 2;
                    const unsigned short *s0, *s1;
                    if (j < 128) {
                        int tok0 = t0 - 64 + j; if (tok0 < 0) tok0 = 0;
                        int tok1 = t0 - 63 + j; if (tok1 < 0) tok1 = 0;
                        s0 = Vu + (size_t)tok0 * DM + h * 64 + g * 8;
                        s1 = Vu + (size_t)tok1 * DM + h * 64 + g * 8;
                    } else {
                        int c0 = cmin + (j - 128); if (c0 > 127) c0 = 127;
                        int c1 = c0 + 1;           if (c1 > 127) c1 = 127;
                        s0 = CVu + (size_t)c0 * DM + h * 64 + g * 8;
                        s1 = CVu + (size_t)c1 * DM + h * 64 + g * 8;
                    }
                    short8 v0 = *(const short8*)s0;
                    short8 v1 = *(const short8*)s1;
#pragma unroll
                    for (int e = 0; e < 8; ++e) {
                        ushort2 pk;
                        pk.x = (unsigned short)v0[e];
                        pk.y = (unsigned short)v1[e];
                        *(ushort2*)&Vts[(g * 8 + e) * PSTR + j] = pk;
                    }
                }
            }
        }
    }

    const __hip_bfloat16* qp = Q + (size_t)(t0 + w * 16 + l16) * DM + h * 64 + quad * 8;
    short8 qf0 = *(const short8*)(qp);
    short8 qf1 = *(const short8*)(qp + 32);

    f32x4 sc[8];
#pragma unroll
    for (int jt = 0; jt < 8; ++jt) {
        int j = jt * 16 + l16;
        int tok = t0 - 64 + j;
        tok = tok < 0 ? 0 : tok;
        const __hip_bfloat16* kp = K + (size_t)tok * DM + h * 64 + quad * 8;
        short8 b0 = *(const short8*)(kp);
        short8 b1 = *(const short8*)(kp + 32);
        f32x4 a = __builtin_amdgcn_mfma_f32_16x16x32_bf16(qf0, b0, (f32x4){0.f,0.f,0.f,0.f}, 0, 0, 0);
        sc[jt]  = __builtin_amdgcn_mfma_f32_16x16x32_bf16(qf1, b1, a, 0, 0, 0);
    }
    f32x4 sc2[2];
#pragma unroll
    for (int jt = 0; jt < 2; ++jt) {
        int c = cmin + jt * 16 + l16;
        if (c > 127) c = 127;
        const __hip_bfloat16* cp = CK + (size_t)c * DM + h * 64 + quad * 8;
        short8 b0 = *(const short8*)(cp);
        short8 b1 = *(const short8*)(cp + 32);
        f32x4 a = __builtin_amdgcn_mfma_f32_16x16x32_bf16(qf0, b0, (f32x4){0.f,0.f,0.f,0.f}, 0, 0, 0);
        sc2[jt] = __builtin_amdgcn_mfma_f32_16x16x32_bf16(qf1, b1, a, 0, 0, 0);
    }

    __syncthreads();

    const int rbase = w * 16 + quad * 4;
    float gl[4], g2[4];
    float mx[4], sm[4], mx2[4], sm2[4];
#pragma unroll
    for (int reg = 0; reg < 4; ++reg) {
        int rr = rbase + reg;
        int t  = t0 + rr;
        float g = G[t * NH + h];
        int rc = (t >= 96) ? ((t - 64) >> 5) : 0;
        gl[reg] = (t > 0)  ? g        : 0.f;
        g2[reg] = (rc > 0) ? (1.f - g) : 0.f;

        int jlo = rr > (64 - t0) ? rr : (64 - t0);
        int jhi = rr + 63;
        float m = -1e30f;
#pragma unroll
        for (int jt = 0; jt < 8; ++jt) {
            int j = jt * 16 + l16;
            float s = (j >= jlo && j <= jhi) ? sc[jt][reg] * scale : -1e30f;
            sc[jt][reg] = s;
            m = fmaxf(m, s);
        }
        mx[reg] = m;

        int nvis = rc < 16 ? rc : 16;
        int clo = rc - nvis, chi = rc - 1;
        float m2 = -1e30f;
#pragma unroll
        for (int jt = 0; jt < 2; ++jt) {
            int c = cmin + jt * 16 + l16;
            float s = (c >= clo && c <= chi) ? sc2[jt][reg] * scale : -1e30f;
            sc2[jt][reg] = s;
            m2 = fmaxf(m2, s);
        }
        mx2[reg] = m2;
    }
#pragma unroll
    for (int off = 1; off <= 8; off <<= 1)
#pragma unroll
        for (int reg = 0; reg < 4; ++reg) {
            mx[reg]  = fmaxf(mx[reg],  __shfl_xor(mx[reg],  off));
            mx2[reg] = fmaxf(mx2[reg], __shfl_xor(mx2[reg], off));
        }
#pragma unroll
    for (int reg = 0; reg < 4; ++reg) {
        float s = 0.f, s2 = 0.f;
#pragma unroll
        for (int jt = 0; jt < 8; ++jt) {
            float p = __expf(sc[jt][reg] - mx[reg]);
            sc[jt][reg] = p;
            s += p;
        }
#pragma unroll
        for (int jt = 0; jt < 2; ++jt) {
            float p = __expf(sc2[jt][reg] - mx2[reg]);
            sc2[jt][reg] = p;
            s2 += p;
        }
        sm[reg] = s; sm2[reg] = s2;
    }
#pragma unroll
    for (int off = 1; off <= 8; off <<= 1)
#pragma unroll
        for (int reg = 0; reg < 4; ++reg) {
            sm[reg]  += __shfl_xor(sm[reg],  off);
            sm2[reg] += __shfl_xor(sm2[reg], off);
        }

#pragma unroll
    for (int reg = 0; reg < 4; ++reg) {
        float f1 = gl[reg] / sm[reg];
        float f2 = g2[reg] / sm2[reg];
        int rowoff = (rbase + reg) * PSTR;
#pragma unroll
        for (int jt = 0; jt < 8; ++jt) {
            __hip_bfloat16 hb = (__hip_bfloat16)(sc[jt][reg] * f1);
            Pls[rowoff + jt * 16 + l16] = *(unsigned short*)&hb;
        }
#pragma unroll
        for (int jt = 0; jt < 2; ++jt) {
            __hip_bfloat16 hb = (__hip_bfloat16)(sc2[jt][reg] * f2);
            Pls[rowoff + 128 + jt * 16 + l16] = *(unsigned short*)&hb;
        }
    }
    asm volatile("s_waitcnt lgkmcnt(0)" ::: "memory");  // wave-private P round-trip

    f32x4 o[4];
#pragma unroll
    for (int nt = 0; nt < 4; ++nt) o[nt] = (f32x4){0.f, 0.f, 0.f, 0.f};
#pragma unroll
    for (int kt = 0; kt < 5; ++kt) {
        short8 a = *(const short8*)&Pls[(w * 16 + l16) * PSTR + kt * 32 + quad * 8];
#pragma unroll
        for (int nt = 0; nt < 4; ++nt) {
            int dd = nt * 16 + l16;
            short8 b = *(const short8*)&Vts[dd * PSTR + kt * 32 + quad * 8];
            o[nt] = __builtin_amdgcn_mfma_f32_16x16x32_bf16(a, b, o[nt], 0, 0, 0);
        }
    }

#pragma unroll
    for (int nt = 0; nt < 4; ++nt) {
#pragma unroll
        for (int reg = 0; reg < 4; ++reg) {
            int row = t0 + rbase + reg;
            int col = h * 64 + nt * 16 + l16;
            Aout[(size_t)row * DM + col] = (__hip_bfloat16)(o[nt][reg]);
        }
    }
}

extern "C" void kernel_launch(void* const* d_in, const int* in_sizes, int n_in,
                              void* d_out, int out_size, void* d_ws, size_t ws_size,
                              hipStream_t stream)
{
    const float* x  = (const float*)d_in[0];
    const float* Wq = (const float*)d_in[1];
    const float* bq = (const float*)d_in[2];
    const float* Wk = (const float*)d_in[3];
    const float* bk = (const float*)d_in[4];
    const float* Wv = (const float*)d_in[5];
    const float* bv = (const float*)d_in[6];
    const float* Wo = (const float*)d_in[7];
    const float* bo = (const float*)d_in[8];
    const float* Wg = (const float*)d_in[9];
    const float* bg = (const float*)d_in[10];
    float* out = (float*)d_out;

    char* ws = (char*)d_ws;
    const size_t MB = 1024 * 1024;
    __hip_bfloat16* xb  = (__hip_bfloat16*)(ws + 0 * MB);   // 8 MB
    __hip_bfloat16* Qb  = (__hip_bfloat16*)(ws + 8 * MB);   // 8 MB
    __hip_bfloat16* Kb  = (__hip_bfloat16*)(ws + 16 * MB);  // 8 MB
    __hip_bfloat16* Vb  = (__hip_bfloat16*)(ws + 24 * MB);  // 8 MB
    __hip_bfloat16* Ab  = (__hip_bfloat16*)(ws + 32 * MB);  // 8 MB
    __hip_bfloat16* Wqb = (__hip_bfloat16*)(ws + 40 * MB);  // 2 MB
    __hip_bfloat16* Wkb = (__hip_bfloat16*)(ws + 42 * MB);  // 2 MB
    __hip_bfloat16* Wvb = (__hip_bfloat16*)(ws + 44 * MB);  // 2 MB
    __hip_bfloat16* Wob = (__hip_bfloat16*)(ws + 46 * MB);  // 2 MB
    __hip_bfloat16* CKb = (__hip_bfloat16*)(ws + 48 * MB);            // 256 KB
    __hip_bfloat16* CVb = (__hip_bfloat16*)(ws + 48 * MB + 256*1024); // 256 KB
    float* Gf           = (float*)(ws + 48 * MB + 512 * 1024);        // 256 KB
    __hip_bfloat16* Wgb = (__hip_bfloat16*)(ws + 48 * MB + 768*1024); // 32 KB

    // cast + gate GEMM fused (gate blocks read fp32 x/Wg directly).
    cast_all<<<dim3(8272), 256, 0, stream>>>(x, Wq, Wk, Wv, Wo, Wg, bg,
                                             xb, Wqb, Wkb, Wvb, Wob, Wgb, Gf);

    // Fused QKV GEMM + chunk-mean epilogue: grid (32, 24); group = blockIdx.y>>3.
    gemm128<__hip_bfloat16><<<dim3(32, 24), 256, 0, stream>>>(
        xb, Wqb, Wkb, Wvb, bq, bk, bv, Qb, Kb, Vb, CKb, CVb);

    attn_mfma<<<dim3(64, 16), 256, 0, stream>>>(Qb, Kb, Vb, CKb, CVb, Gf, Ab);

    // Output GEMM: 128x64 tiles (BK=32), grid (32, 16).
    gemm_n64<float><<<dim3(32, 16), 256, 0, stream>>>(Ab, Wob, bo, out);
}